// Round 15
// baseline (300.517 us; speedup 1.0000x reference)
//
#include <hip/hip_runtime.h>
#include <hip/hip_bf16.h>

// EdgeConv: N=16384 points, C=64, D=64, K=16 neighbors. All I/O fp32.
// Pipeline (R10 skeleton -- best known):
//   memset(counts) -> [count | prep fused] -> scan -> scatter -> knn -> edge
// R15 knn: 4 SORTED-ADJACENT QUERIES PER WAVE, full-wave ops (R14's 16-lane
// subgroups regressed: divergent per-group loops execute the union path at
// 1/4 utilization). One wave enumerates shells/runs around the UNION cube
// once (prefix-scan, binary search, spos load shared), screens each
// 64-candidate batch against all 4 queries. Selection = R12's flood-immune
// append-and-flush per query (4x64-slot LDS buffers; flush = bitonic64 +
// merge32, exact top-16 of union). Termination per query vs common processed
// cube (valid bound; 1e-4 margin). Distance/keys identical to R10/R12.

#define NPTS 16384
#define CH 64

#define GLO  (-4.5f)
#define GH   0.28125f          // 9/32
#define INVH 3.5555555556f     // 32/9
#define GDIM 32
#define GCELLS (GDIM * GDIM * GDIM)

typedef __attribute__((ext_vector_type(8))) short short8;
typedef __attribute__((ext_vector_type(4))) float floatx4;

__device__ __forceinline__ unsigned short f2bf(float f) {
    unsigned u = __float_as_uint(f);
    u += 0x7FFFu + ((u >> 16) & 1u);   // RNE
    return (unsigned short)(u >> 16);
}
__device__ __forceinline__ float bf2f(unsigned short u) {
    return __uint_as_float(((unsigned)u) << 16);
}
// wave64 inclusive scan via DPP (validated R11/R12)
__device__ __forceinline__ unsigned wave_iscan(unsigned x) {
    x += (unsigned)__builtin_amdgcn_update_dpp(0, (int)x, 0x111, 0xF, 0xF, true);
    x += (unsigned)__builtin_amdgcn_update_dpp(0, (int)x, 0x112, 0xF, 0xF, true);
    x += (unsigned)__builtin_amdgcn_update_dpp(0, (int)x, 0x114, 0xF, 0xF, true);
    x += (unsigned)__builtin_amdgcn_update_dpp(0, (int)x, 0x118, 0xF, 0xF, true);
    x += (unsigned)__builtin_amdgcn_update_dpp(0, (int)x, 0x142, 0xA, 0xF, true);
    x += (unsigned)__builtin_amdgcn_update_dpp(0, (int)x, 0x143, 0xC, 0xF, true);
    return x;
}
__device__ __forceinline__ int cell_of(float x, float y, float z) {
    int cx = (int)floorf((x - GLO) * INVH);
    int cy = (int)floorf((y - GLO) * INVH);
    int cz = (int)floorf((z - GLO) * INVH);
    cx = min(max(cx, 0), GDIM - 1);
    cy = min(max(cy, 0), GDIM - 1);
    cz = min(max(cz, 0), GDIM - 1);
    return (cz * GDIM + cy) * GDIM + cx;
}

// ---------------------------------------------------------------------------
// Fused: blocks 0..63 = grid count (atomics); blocks 64..319 = prep GEMM
// ---------------------------------------------------------------------------
__global__ __launch_bounds__(256) void count_prep_kernel(const float* __restrict__ pos,
                                                         int* __restrict__ counts,
                                                         const float* __restrict__ x,
                                                         const float* __restrict__ W1,
                                                         const float* __restrict__ b1,
                                                         float* __restrict__ vout,
                                                         unsigned short* __restrict__ ubuf) {
    __shared__ unsigned short Wct[128 * 72];
    __shared__ unsigned short Abuf[64 * 72];
    __shared__ float Wraw[128 * 64];

    const int t = threadIdx.x;
    if (blockIdx.x < 64) {
        const int i = blockIdx.x * 256 + t;
        atomicAdd(&counts[cell_of(pos[i * 3], pos[i * 3 + 1], pos[i * 3 + 2])], 1);
        return;
    }
    const int bid  = blockIdx.x - 64;
    const int lane = t & 63;
    const int w    = t >> 6;

    {
        const float4* W1v = (const float4*)W1;
        float4* Wr4 = (float4*)Wraw;
#pragma unroll
        for (int i = 0; i < 8; ++i) Wr4[i * 256 + t] = W1v[i * 256 + t];
    }
    __syncthreads();
    {
        const int n = t & 127;
        const int ks = (t >> 7) * 32;
#pragma unroll
        for (int i = 0; i < 32; ++i) {
            const int k = ks + i;
            float val;
            if (n < 64) val = Wraw[k * 64 + n] - Wraw[(64 + k) * 64 + n];
            else        val = Wraw[(64 + k) * 64 + (n - 64)];
            Wct[n * 72 + k] = f2bf(val);
        }
    }
    {
        const int col = t & 63;
#pragma unroll
        for (int i = 0; i < 16; ++i) {
            const int r2 = (t >> 6) + 4 * i;
            const int gp = bid * 64 + r2;
            Abuf[r2 * 72 + col] = f2bf(x[(size_t)gp * CH + col]);
        }
    }
    __syncthreads();

    const int m16 = lane & 15;
    const int q   = lane >> 4;

    floatx4 acc[8];
#pragma unroll
    for (int nt = 0; nt < 8; ++nt) acc[nt] = (floatx4){0.f, 0.f, 0.f, 0.f};

#pragma unroll
    for (int kk = 0; kk < 64; kk += 32) {
        const short8 a = *(const short8*)(Abuf + (w * 16 + m16) * 72 + kk + q * 8);
#pragma unroll
        for (int nt = 0; nt < 8; ++nt) {
            const short8 b = *(const short8*)(Wct + (nt * 16 + m16) * 72 + kk + q * 8);
            acc[nt] = __builtin_amdgcn_mfma_f32_16x16x32_bf16(a, b, acc[nt], 0, 0, 0);
        }
    }

#pragma unroll
    for (int nt = 0; nt < 8; ++nt) {
        const int n = nt * 16 + m16;
#pragma unroll
        for (int r = 0; r < 4; ++r) {
            const int gp = bid * 64 + w * 16 + q * 4 + r;
            if (n < 64) vout[(size_t)gp * CH + n] = acc[nt][r] + b1[n];
            else        ubuf[(size_t)gp * CH + (n - 64)] = f2bf(acc[nt][r]);
        }
    }
}

// starts has GCELLS+1 entries; starts[GCELLS] = NPTS sentinel (run ends).
__global__ __launch_bounds__(1024) void scan_kernel(const int* __restrict__ counts,
                                                    int* __restrict__ starts,
                                                    int* __restrict__ cursor) {
    __shared__ int lds[1024];
    const int t = threadIdx.x;
    int4 v[8];
    const int4* c4 = (const int4*)counts + t * 8;
#pragma unroll
    for (int i = 0; i < 8; ++i) v[i] = c4[i];
    int sum = 0;
#pragma unroll
    for (int i = 0; i < 8; ++i) sum += v[i].x + v[i].y + v[i].z + v[i].w;
    lds[t] = sum;
    __syncthreads();
    for (int off = 1; off < 1024; off <<= 1) {
        int x = 0;
        if (t >= off) x = lds[t - off];
        __syncthreads();
        lds[t] += x;
        __syncthreads();
    }
    int pre = (t == 0) ? 0 : lds[t - 1];
    int4* s4 = (int4*)starts + t * 8;
    int4* u4 = (int4*)cursor + t * 8;
#pragma unroll
    for (int i = 0; i < 8; ++i) {
        int4 o;
        o.x = pre; pre += v[i].x;
        o.y = pre; pre += v[i].y;
        o.z = pre; pre += v[i].z;
        o.w = pre; pre += v[i].w;
        s4[i] = o;
        u4[i] = o;
    }
    if (t == 1023) starts[GCELLS] = pre;   // == NPTS
}

__global__ __launch_bounds__(256) void grid_scatter_kernel(const float* __restrict__ pos,
                                                           int* __restrict__ cursor,
                                                           float4* __restrict__ spos,
                                                           unsigned short* __restrict__ sidx) {
    const int i = blockIdx.x * 256 + threadIdx.x;
    const float a = pos[i * 3], b = pos[i * 3 + 1], c = pos[i * 3 + 2];
    const int dst = atomicAdd(&cursor[cell_of(a, b, c)], 1);
    spos[dst] = make_float4(a, b, c, a * a + b * b + c * c);  // same sq expr as query side
    sidx[dst] = (unsigned short)i;
}

// ---------------------------------------------------------------------------
// Grid KNN: 1 wave per 4 SORTED-ADJACENT queries. Shell enumeration/scan/
// binary-search/load shared (union cube); screen + append-flush per query.
// ---------------------------------------------------------------------------
#define SENT 0xFF800000FFFFFFFFULL   // key(+inf) | idx-all-ones
#define QPW 4

__global__ __launch_bounds__(64) void knn_grid_kernel(const float4* __restrict__ spos,
                                                      const unsigned short* __restrict__ sidx,
                                                      const int* __restrict__ starts,
                                                      unsigned short* __restrict__ knn_out) {
    __shared__ int lds_ex[64];
    __shared__ int lds_st[64];
    __shared__ unsigned long long bufs[QPW * 64];
    const int lane = threadIdx.x;
    const int sq0  = blockIdx.x * QPW;

    float qx[QPW], qy[QPW], qz[QPW], sqi[QPW];
    int qrow[QPW];
    int cminx = GDIM, cmaxx = -1, cminy = GDIM, cmaxy = -1, cminz = GDIM, cmaxz = -1;
#pragma unroll
    for (int r = 0; r < QPW; ++r) {
        const float4 qv = spos[sq0 + r];
        qx[r] = qv.x; qy[r] = qv.y; qz[r] = qv.z; sqi[r] = qv.w;
        qrow[r] = (int)sidx[sq0 + r];
        const int cx = min(max((int)floorf((qv.x - GLO) * INVH), 0), GDIM - 1);
        const int cy = min(max((int)floorf((qv.y - GLO) * INVH), 0), GDIM - 1);
        const int cz = min(max((int)floorf((qv.z - GLO) * INVH), 0), GDIM - 1);
        cminx = min(cminx, cx); cmaxx = max(cmaxx, cx);
        cminy = min(cminy, cy); cmaxy = max(cmaxy, cy);
        cminz = min(cminz, cz); cmaxz = max(cmaxz, cz);
    }

    unsigned long long list[QPW];
    float tau[QPW];
    int nbuf[QPW];
    bool done[QPW];
#pragma unroll
    for (int r = 0; r < QPW; ++r) {
        list[r] = SENT;
        tau[r]  = __uint_as_float(0x7F800000u);   // +INF
        nbuf[r] = 0;
        done[r] = false;
    }

    // exact merge of query r's buffered candidates into its running top-16
    auto do_flush = [&](int r) {
        unsigned long long ck = (lane < nbuf[r]) ? bufs[r * 64 + lane] : SENT;
#pragma unroll
        for (int k = 2; k <= 64; k <<= 1) {
#pragma unroll
            for (int jj = k >> 1; jj >= 1; jj >>= 1) {
                const unsigned long long o = __shfl_xor(ck, jj);
                const bool takeMin = (((lane & k) == 0) == ((lane & jj) == 0));
                const unsigned long long mn = (ck < o) ? ck : o;
                const unsigned long long mx = (ck < o) ? o : ck;
                ck = takeMin ? mn : mx;
            }
        }
        const unsigned long long cv = __shfl(ck, 31 - lane);
        unsigned long long m = SENT;
        if (lane < 16) m = list[r];
        else if (lane < 32) m = cv;
#pragma unroll
        for (int jj = 16; jj >= 1; jj >>= 1) {
            const unsigned long long o = __shfl_xor(m, jj);
            const unsigned long long mn = (m < o) ? m : o;
            const unsigned long long mx = (m < o) ? o : m;
            m = ((lane & jj) == 0) ? mn : mx;
        }
        list[r] = m;
        const unsigned thi = (unsigned)__builtin_amdgcn_readlane(
            (int)(unsigned)(list[r] >> 32), 15);
        const unsigned fb = (thi >= 0x80000000u) ? (thi & 0x7FFFFFFFu) : ~thi;
        tau[r] = __uint_as_float(fb);
        nbuf[r] = 0;
    };

    int pax = 1, pbx = 0, pay = 1, pby = 0, paz = 1, pbz = 0;  // empty prev cube

    for (int s = 1; s < GDIM + 1; ++s) {
        const int ax = max(cminx - s, 0), bx = min(cmaxx + s, GDIM - 1);
        const int ay = max(cminy - s, 0), by = min(cmaxy + s, GDIM - 1);
        const int az = max(cminz - s, 0), bz = min(cmaxz + s, GDIM - 1);
        const int dy = by - ay + 1, dz = bz - az + 1;
        const int npair = dy * dz;
        const float invdy = 1.0f / (float)dy;

        for (int pb = 0; pb < npair; pb += 64) {
            const int pair = pb + lane;
            int stA = 0, lenA = 0, stB = 0, lenB = 0;
            if (pair < npair) {
                const int czo = (int)(((float)pair + 0.5f) * invdy);
                const int cyo = pair - czo * dy;
                const int cy = ay + cyo, cz = az + czo;
                const int rowb = (cz * GDIM + cy) * GDIM;
                const bool inner = cy >= pay && cy <= pby && cz >= paz && cz <= pbz;
                const int bA = inner ? (pax - 1) : bx;
                if (bA >= ax) {
                    stA  = starts[rowb + ax];
                    lenA = starts[rowb + bA + 1] - stA;
                }
                if (inner) {
                    const int aB = pbx + 1;
                    if (bx >= aB) {
                        stB  = starts[rowb + aB];
                        lenB = starts[rowb + bx + 1] - stB;
                    }
                }
            }
#pragma unroll
            for (int setsel = 0; setsel < 2; ++setsel) {
                const int st  = setsel ? stB  : stA;
                const int len = setsel ? lenB : lenA;
                if (__ballot(len > 0) == 0ULL) continue;
                const unsigned pfx = wave_iscan((unsigned)len);  // DPP scan
                const int T = __builtin_amdgcn_readlane((int)pfx, 63);
                lds_ex[lane] = (int)pfx - len;
                lds_st[lane] = st;

                for (int b0 = 0; b0 < T; b0 += 64) {
                    const int p = b0 + lane;
                    int j = 0;
#pragma unroll
                    for (int stp = 32; stp >= 1; stp >>= 1) {
                        const int m = j + stp;
                        if (lds_ex[m] <= p) j = m;
                    }
                    int idx = lds_st[j] + (p - lds_ex[j]);
                    idx = min(idx, NPTS - 1);
                    const bool active = p < T;
                    const float4 pt = spos[idx];
                    const int jorig = (int)sidx[idx];

#pragma unroll
                    for (int r = 0; r < QPW; ++r) {
                        if (done[r]) continue;   // wave-uniform
                        // reference-formula distance (identical to R10)
                        const float dot = fmaf(qx[r], pt.x,
                                               fmaf(qy[r], pt.y, qz[r] * pt.z));
                        const float d = fmaf(-2.0f, dot, sqi[r] + pt.w);
                        const bool cand = active && (jorig != qrow[r]) &&
                                          (d <= tau[r]);
                        const unsigned long long mask = __ballot(cand);
                        if (mask) {
                            const int cnt = __popcll(mask);
                            if (nbuf[r] + cnt > 64) do_flush(r);   // wave-uniform
                            if (cand) {
                                unsigned kd = __float_as_uint(d);
                                kd = ((int)kd < 0) ? ~kd : (kd | 0x80000000u);
                                const unsigned long long key =
                                    (((unsigned long long)kd) << 32) |
                                    (unsigned)jorig;
                                const int rank =
                                    __popcll(mask & ((1ULL << lane) - 1ULL));
                                bufs[r * 64 + nbuf[r] + rank] = key;
                            }
                            nbuf[r] += cnt;
                        }
                    }
                }
            }
        }

        // per-query flush + termination vs the COMMON processed cube
        bool alldone = true;
        const bool fullcube = (ax == 0 && bx == GDIM - 1 && ay == 0 &&
                               by == GDIM - 1 && az == 0 && bz == GDIM - 1);
#pragma unroll
        for (int r = 0; r < QPW; ++r) {
            if (!done[r]) {
                if (nbuf[r]) do_flush(r);
                const float BIG = 1e30f;
                float dout = BIG;
                if (ax > 0)        dout = fminf(dout, qx[r] - (GLO + ax * GH));
                if (bx < GDIM - 1) dout = fminf(dout, (GLO + (bx + 1) * GH) - qx[r]);
                if (ay > 0)        dout = fminf(dout, qy[r] - (GLO + ay * GH));
                if (by < GDIM - 1) dout = fminf(dout, (GLO + (by + 1) * GH) - qy[r]);
                if (az > 0)        dout = fminf(dout, qz[r] - (GLO + az * GH));
                if (bz < GDIM - 1) dout = fminf(dout, (GLO + (bz + 1) * GH) - qz[r]);
                if (dout * dout > tau[r] + 1e-4f || fullcube) done[r] = true;
                else alldone = false;
            }
        }
        if (alldone) break;
        pax = ax; pbx = bx; pay = ay; pby = by; paz = az; pbz = bz;
    }

#pragma unroll
    for (int r = 0; r < QPW; ++r)
        if (lane < 16)
            knn_out[qrow[r] * 16 + lane] =
                (unsigned short)(list[r] & 0xFFFFULL);
}

// ---------------------------------------------------------------------------
// edge: block = 8 points (128 edge rows). h = relu(v_i + u_j) staged bf16 in
// LDS; GEMM2 (128x64)@(64x64) via MFMA; max over each point's 16 rows; +b2.
// ---------------------------------------------------------------------------
__global__ __launch_bounds__(256) void edge_kernel(const unsigned short* __restrict__ ubuf,
                                                   const float* __restrict__ W2,
                                                   const float* __restrict__ b2,
                                                   const unsigned short* __restrict__ knn,
                                                   float* __restrict__ out) {
    __shared__ unsigned short h[128 * 72];
    __shared__ unsigned short W2t[64 * 72];

    const int t    = threadIdx.x;
    const int lane = t & 63;
    const int w    = t >> 6;

    {
        const int n = t & 63;
        const int kb = (t >> 6) * 16;
#pragma unroll
        for (int i = 0; i < 16; ++i) {
            const int k = kb + i;
            W2t[n * 72 + k] = f2bf(W2[k * 64 + n]);
        }
    }
    {
        const int k = t >> 4;
        const int c = t & 15;
#pragma unroll
        for (int i = 0; i < 8; ++i) {
            const int gn = blockIdx.x * 8 + i;
            const int gj = (int)knn[gn * 16 + k];
            const float4  vv = ((const float4*)(out + (size_t)gn * CH))[c];
            const ushort4 uu = ((const ushort4*)(ubuf + (size_t)gj * CH))[c];
            ushort4 hv;
            hv.x = f2bf(fmaxf(vv.x + bf2f(uu.x), 0.f));
            hv.y = f2bf(fmaxf(vv.y + bf2f(uu.y), 0.f));
            hv.z = f2bf(fmaxf(vv.z + bf2f(uu.z), 0.f));
            hv.w = f2bf(fmaxf(vv.w + bf2f(uu.w), 0.f));
            const int r2 = i * 16 + k;
            *(ushort4*)(h + r2 * 72 + c * 4) = hv;
        }
    }
    __syncthreads();

    const int m16 = lane & 15;
    const int q   = lane >> 4;

    floatx4 acc[2][4];
#pragma unroll
    for (int i = 0; i < 2; ++i)
#pragma unroll
        for (int nt = 0; nt < 4; ++nt) acc[i][nt] = (floatx4){0.f, 0.f, 0.f, 0.f};

#pragma unroll
    for (int kk = 0; kk < 64; kk += 32) {
        const short8 a0 = *(const short8*)(h + ((w * 2 + 0) * 16 + m16) * 72 + kk + q * 8);
        const short8 a1 = *(const short8*)(h + ((w * 2 + 1) * 16 + m16) * 72 + kk + q * 8);
#pragma unroll
        for (int nt = 0; nt < 4; ++nt) {
            const short8 b = *(const short8*)(W2t + (nt * 16 + m16) * 72 + kk + q * 8);
            acc[0][nt] = __builtin_amdgcn_mfma_f32_16x16x32_bf16(a0, b, acc[0][nt], 0, 0, 0);
            acc[1][nt] = __builtin_amdgcn_mfma_f32_16x16x32_bf16(a1, b, acc[1][nt], 0, 0, 0);
        }
    }

#pragma unroll
    for (int i = 0; i < 2; ++i) {
        const int mt = w * 2 + i;
        const int gn = blockIdx.x * 8 + mt;
#pragma unroll
        for (int nt = 0; nt < 4; ++nt) {
            float m0 = fmaxf(fmaxf(acc[i][nt][0], acc[i][nt][1]),
                             fmaxf(acc[i][nt][2], acc[i][nt][3]));
            m0 = fmaxf(m0, __shfl_xor(m0, 16));
            m0 = fmaxf(m0, __shfl_xor(m0, 32));
            if (lane < 16)
                out[(size_t)gn * CH + nt * 16 + lane] = m0 + b2[nt * 16 + lane];
        }
    }
}

extern "C" void kernel_launch(void* const* d_in, const int* in_sizes, int n_in,
                              void* d_out, int out_size, void* d_ws, size_t ws_size,
                              hipStream_t stream) {
    const float* x   = (const float*)d_in[0];
    const float* pos = (const float*)d_in[1];
    const float* W1  = (const float*)d_in[2];
    const float* b1  = (const float*)d_in[3];
    const float* W2  = (const float*)d_in[4];
    const float* b2  = (const float*)d_in[5];
    float* out = (float*)d_out;

    char* ws = (char*)d_ws;
    unsigned short* knn  = (unsigned short*)ws;                    // 512 KB @ 0
    unsigned short* ubuf = (unsigned short*)(ws + 524288);         // 2 MB
    int*    counts = (int*)(ws + 2621440);                         // 128 KB
    int*    starts = (int*)(ws + 2752512);                         // 128 KB + sentinel
    int*    cursor = (int*)(ws + 2883600);                         // 128 KB
    float4* spos   = (float4*)(ws + 3014672);                      // 256 KB
    unsigned short* sidx = (unsigned short*)(ws + 3276816);        // 32 KB

    hipMemsetAsync(counts, 0, GCELLS * sizeof(int), stream);
    count_prep_kernel<<<320, 256, 0, stream>>>(pos, counts, x, W1, b1, out, ubuf);
    scan_kernel<<<1, 1024, 0, stream>>>(counts, starts, cursor);
    grid_scatter_kernel<<<NPTS / 256, 256, 0, stream>>>(pos, cursor, spos, sidx);
    knn_grid_kernel<<<NPTS / QPW, 64, 0, stream>>>(spos, sidx, starts, knn);
    edge_kernel<<<NPTS / 8, 256, 0, stream>>>(ubuf, W2, b2, knn, out);
}